// Round 8
// baseline (405.261 us; speedup 1.0000x reference)
//
#include <hip/hip_runtime.h>
#include <hip/hip_bf16.h>
#include <math.h>

// ============================================================================
// MinimalNetwork, round 22: pipeline consolidation (r21 et-MFMA failed
// correctness -> reverted; fused internals are byte-identical to r20/passing).
// r19/r20 post-mortem: fused=154us but TOTAL=373 -> ~220us lives OUTSIDE
// fused (radial kernel + h_bf 54MB roundtrip + 11 other dispatches).
// Changes (all math bit-identical to r20):
//   - radial MLP folded into fused prologue (same 64-edge/block partition);
//     LDS overlay [sWr 28.7K | sbas 2.5K | hA 17.4K | hB 17.4K] = 66K fits in
//     the 81.4K block (all fused buffers dead during prologue). hf regs
//     loaded from LDS; h_bf global buffer + radial launch REMOVED.
//   - c3_build+c3_norm merged (per-chunk block, LDS double buffers, no
//     Tre/Tim global roundtrip).
//   - prep_w3t+prep_wt merged (idx-routed).
//   - dispatches 12 -> 8.
// Kill criteria: total >=370 -> unfuse radial; absmax fail -> r20 revert.
// ============================================================================

#define FEATD 72
#define NCOL 1216
#define SWISH_SCALE 1.679177f

typedef __attribute__((ext_vector_type(8))) short bf16x8;
typedef __attribute__((ext_vector_type(4))) float f32x4;

// ---- 19 (lo,li,lf) chunks; CB_OFF = offsets into the C3 coefficient pool ----
constexpr int NCOMBO = 19;
constexpr int CB_LO[NCOMBO] = {0,0,0,1,1,1,1,1,1,1,2,2,2,2,2,2,2,2,2};
constexpr int CB_LI[NCOMBO] = {0,1,2,0,1,1,1,2,2,2,0,1,1,1,2,2,2,2,2};
constexpr int CB_LF[NCOMBO] = {0,1,2,1,0,1,2,1,2,3,2,1,2,3,0,1,2,3,4};
constexpr int CB_OFF[NCOMBO] = {0,1,10,35,44,53,80,125,170,245,350,375,420,495,600,625,700,825,1000};
constexpr int CB_SZ[NCOMBO]  = {1,9,25,9,9,27,45,45,75,105,25,45,75,105,25,75,125,175,225};
constexpr int C3TOT = 1225;

constexpr int C3OFFT[3][3][5] = {
  { {0,-1,-1,-1,-1}, {-1,1,-1,-1,-1}, {-1,-1,10,-1,-1} },
  { {-1,35,-1,-1,-1}, {44,53,80,-1,-1}, {-1,125,170,245,-1} },
  { {-1,-1,350,-1,-1}, {-1,375,420,495,-1}, {600,625,700,825,1000} }
};
constexpr int ROFFT[3][3] = {{0,64,128},{192,256,448},{640,704,896}};
constexpr int FOFFT[3]   = {0,8,32};

__device__ const double d_fact[11] = {1.,1.,2.,6.,24.,120.,720.,5040.,40320.,362880.,3628800.};

// ---------------------------------------------------------------------------
// Wigner 3j (complex basis, Racah) in double precision + real change of basis
// ---------------------------------------------------------------------------
__device__ double w3j_entry(int j1,int j2,int j3,int m1,int m2,int m3){
  if (m1+m2+m3 != 0) return 0.0;
  int dj = j1-j2; if (dj<0) dj=-dj;
  if (j3 < dj || j3 > j1+j2) return 0.0;
  int t1 = j2 - m1 - j3, t2 = j1 + m2 - j3;
  int kmin = 0; if (t1>kmin) kmin=t1; if (t2>kmin) kmin=t2;
  int kmax = j1+j2-j3; if (j1-m1<kmax) kmax=j1-m1; if (j2+m2<kmax) kmax=j2+m2;
  double s = 0.0;
  for (int k=kmin;k<=kmax;++k){
    double den = d_fact[k]*d_fact[k-t1]*d_fact[k-t2]*d_fact[j1+j2-j3-k]
               * d_fact[j1-m1-k]*d_fact[j2+m2-k];
    s += ((k&1)? -1.0:1.0)/den;
  }
  double pref = sqrt(d_fact[j1+j2-j3]*d_fact[j1-j2+j3]*d_fact[-j1+j2+j3]/d_fact[j1+j2+j3+1]
               * d_fact[j1+m1]*d_fact[j1-m1]*d_fact[j2+m2]*d_fact[j2-m2]
               * d_fact[j3+m3]*d_fact[j3-m3]);
  int ex = j1-j2-m3;
  if (ex & 1) pref = -pref;
  return pref*s;
}

__device__ void cob(int l, int r, int c, double& re, double& im){
  re = 0.0; im = 0.0;
  int mr = r - l, mc = c - l;
  const double s = 0.70710678118654752440;
  if (mr == 0) { if (mc == 0) re = 1.0; return; }
  if (mr > 0) {
    if (mc == mr)       re = (mr & 1) ? -s : s;
    else if (mc == -mr) re = s;
  } else {
    int m = -mr;
    if (mc == -m)      im = s;
    else if (mc == m)  im = (m & 1) ? s : -s;
  }
}

// One block per chunk: compute all elements in LDS (double), normalize, emit.
__global__ void c3_combined_kernel(float* __restrict__ C3f){
  __shared__ double sre[225], sim[225];
  const int c = blockIdx.x;
  const int lo = CB_LO[c], li = CB_LI[c], lf = CB_LF[c];
  const int off = CB_OFF[c], sz = CB_SZ[c];
  const int n2 = 2*li+1, n3 = 2*lf+1;
  const int t = threadIdx.x;

  for (int p=t; p<sz; p+=64){
    int a = p/(n2*n3), b = (p/n3)%n2, g = p%n3;
    double re=0.0, im=0.0;
    for (int m1=-lo; m1<=lo; ++m1){
      for (int m2=-li; m2<=li; ++m2){
        int m3 = -m1-m2;
        if (m3 < -lf || m3 > lf) continue;
        double w = w3j_entry(lo,li,lf,m1,m2,m3);
        if (w == 0.0) continue;
        double r1,i1,r2,i2,r3,i3;
        cob(lo, a, m1+lo, r1,i1);
        cob(li, b, m2+li, r2,i2);
        cob(lf, g, m3+lf, r3,i3);
        double rr = r1*r2 - i1*i2, ri = r1*i2 + i1*r2;
        double fr = rr*r3 - ri*i3, fi = rr*i3 + ri*r3;
        re += fr*w; im += fi*w;
      }
    }
    sre[p] = re; sim[p] = im;
  }
  __syncthreads();
  double s2r=0.0, s2i=0.0;
  for (int p=t; p<sz; p+=64){ double x=sre[p], y=sim[p]; s2r+=x*x; s2i+=y*y; }
  for (int m=1; m<64; m<<=1){ s2r += __shfl_xor(s2r, m, 64); s2i += __shfl_xor(s2i, m, 64); }
  bool useRe = (s2r >= s2i);
  double n = sqrt(useRe ? s2r : s2i);
  double inv = (n > 0.0) ? 1.0/n : 1.0;
  for (int p=t; p<sz; p+=64){
    double v = useRe ? sre[p] : sim[p];
    C3f[off+p] = (float)(v*inv);
  }
}

// ---------------------------------------------------------------------------
// Combined weight repack (idx-routed): W3t chunks + W1t/W2t, all pitch-128,
// 0.1 folded, PRE-SWIZZLED: unit16 = (row*16 + (k>>3)) ^ (row&7).
// ---------------------------------------------------------------------------
__global__ __launch_bounds__(256) void prep_combined_kernel(
    const float* __restrict__ W3, const float* __restrict__ W1,
    const float* __restrict__ W2, __hip_bfloat16* __restrict__ W3t,
    __hip_bfloat16* __restrict__ W1t, __hip_bfloat16* __restrict__ W2t)
{
  int idx = blockIdx.x*256 + threadIdx.x;
  constexpr int NW3 = 1216*128;      // 155648
  constexpr int HALF = 112*128;      // 14336
  if (idx < NW3){
    int cp = idx >> 7, k = idx & 127;
    int chunk = cp >> 6, r = cp & 63;
    int lo = CB_LO[chunk], li = CB_LI[chunk], lf = CB_LF[chunk];
    int lmin = lo<li ? lo : li;
    int nlf = 2*lmin+1;
    int fi = lf - (lo>li ? lo-li : li-lo);
    int c = ROFFT[lo][li] + r*nlf + fi;
    float v = (k < 100) ? 0.1f*W3[(size_t)k*NCOL + c] : 0.f;
    int swz = (r*16 + (k>>3)) ^ (r&7);
    W3t[(size_t)chunk*8192 + swz*8 + (k&7)] = __float2bfloat16(v);
  } else if (idx < NW3 + 2*HALF){
    int r2 = idx - NW3;
    const float* W = (r2 < HALF) ? W1 : W2;
    __hip_bfloat16* Wt = (r2 < HALF) ? W1t : W2t;
    int r = (r2 < HALF) ? r2 : r2 - HALF;
    int o = r >> 7, k = r & 127;
    float v = (o < 100 && k < 100) ? 0.1f*W[k*100+o] : 0.f;
    int swz = (o*16 + (k>>3)) ^ (o&7);
    Wt[swz*8 + (k&7)] = __float2bfloat16(v);
  }
}

// ---------------------------------------------------------------------------
// CSR of edges by target node
// ---------------------------------------------------------------------------
__global__ __launch_bounds__(256) void hist_kernel(const int* __restrict__ ei,
                                                   int* __restrict__ deg, int E){
  int e = blockIdx.x*256 + threadIdx.x;
  if (e < E) atomicAdd(&deg[ei[E+e]], 1);
}

__global__ __launch_bounds__(256) void scan_kernel(const int* __restrict__ deg,
                                                   int* __restrict__ off,
                                                   int* __restrict__ cursor, int N, int E){
  __shared__ int part[256], spref[256];
  const int t = threadIdx.x;
  const int CH = (N + 255)/256;
  int lo = t*CH, hi = lo+CH < N ? lo+CH : N;
  int s = 0;
  for (int n=lo; n<hi; ++n) s += deg[n];
  part[t] = s;
  __syncthreads();
  if (t == 0){
    int run = 0;
    for (int i=0;i<256;++i){ spref[i] = run; run += part[i]; }
  }
  __syncthreads();
  int run = spref[t];
  for (int n=lo; n<hi; ++n){ off[n] = run; cursor[n] = run; run += deg[n]; }
  if (t == 255) off[N] = E;
}

__global__ __launch_bounds__(256) void fill_kernel(const int* __restrict__ ei,
                                                   int* __restrict__ cursor,
                                                   int* __restrict__ eid, int E){
  int e = blockIdx.x*256 + threadIdx.x;
  if (e < E){
    int idx = atomicAdd(&cursor[ei[E+e]], 1);
    eid[idx] = e;
  }
}

// ---------------------------------------------------------------------------
// Gather: one 64-lane wave per node; writes every output element exactly once.
// ---------------------------------------------------------------------------
__global__ __launch_bounds__(64) void gather_kernel(const float* __restrict__ msg,
                                                    const int* __restrict__ off,
                                                    const int* __restrict__ eid,
                                                    float* __restrict__ out, int N){
  const int n = blockIdx.x;
  const int t = threadIdx.x;
  const int s = off[n], e1 = off[n+1];
  float a0 = 0.f, a1 = 0.f;
  for (int i=s; i<e1; ++i){
    const float* m = msg + (size_t)eid[i]*FEATD;
    a0 += m[t];
    if (t < 8) a1 += m[64+t];
  }
  out[(size_t)n*FEATD + t] = a0;
  if (t < 8) out[(size_t)n*FEATD + 64 + t] = a1;
}

// ---------------------------------------------------------------------------
// Fused radial + GEMM + TP. Radial prologue uses an LDS overlay (66K) of the
// fused buffers (81444 B total, 2 blocks/CU). Fused internals = r20 (passing).
// ---------------------------------------------------------------------------
constexpr int OF_W   = 0;         // 16384: staged W3t chunk (swizzled)
constexpr int OF_RT  = 16384;     // 64*68 f32 = 17408
constexpr int OF_ACC = 33792;     // 64*40 f32 = 10240 (live LO-group slice)
constexpr int OF_F   = 44032;     // 64*76 f32 = 19456
constexpr int OF_KV  = 63488;     // 2 x 64*25 f32 = 12800 (double-buffered)
constexpr int OF_C3  = 76288;     // 1225 f32 = 4900
constexpr int OF_SRC = 81188;     // 64 int = 256
constexpr int SMEM_SZ = 81444;    // <= 81920 -> 2 blocks/CU

// radial overlay (prologue only; everything dead at that point)
constexpr int OF_RW   = 0;        // 28672: staged W1t/W2t
constexpr int OF_BAS  = 28672;    // 640 f32 = 2560
constexpr int OF_HA   = 31232;    // 64*136 bf16 = 17408
constexpr int OF_HB   = 48640;    // 64*136 bf16 = 17408 -> ends 66048

__device__ __forceinline__ float swishf(float s){
  return SWISH_SCALE * s / (1.f + __expf(-s));
}

// stage 28672B pre-swizzled Wt: 7 x global_load_lds(16B) per thread
__device__ __forceinline__ void stage_w(const __hip_bfloat16* __restrict__ Wt,
                                        char* sW, int t)
{
  const int lane = t & 63, wv = t >> 6;
  const char* g = (const char*)Wt;
  #pragma unroll
  for (int i=0; i<7; ++i){
    const char* gsrc = g + (i*256 + wv*64 + lane)*16;
    __builtin_amdgcn_global_load_lds(
        (const __attribute__((address_space(1))) unsigned int*)gsrc,
        (__attribute__((address_space(3))) unsigned int*)(sW + i*4096 + wv*1024),
        16, 0, 0);
  }
}

__device__ __forceinline__ void radial_layer_lds(
    const __hip_bfloat16* __restrict__ sIn,   // [64][136] bf16, rows e
    const char* __restrict__ sW,              // staged Wt (swizzled, pitch 128)
    __hip_bfloat16* __restrict__ sOut,        // [64][136] bf16
    int wv, int lr, int lq)
{
  bf16x8 bf[4];
  #pragma unroll
  for (int ks=0; ks<4; ++ks)
    bf[ks] = *(const bf16x8*)&sIn[(wv*16+lr)*136 + ks*32 + lq*8];
  f32x4 acc[7] = {};
  #pragma unroll
  for (int ks=0; ks<4; ++ks)
    #pragma unroll
    for (int ot=0; ot<7; ++ot){
      const int row = ot*16 + lr;
      const int u = (row*16 + ks*4 + lq) ^ (row & 7);
      bf16x8 a = *(const bf16x8*)(sW + u*16);
      acc[ot] = __builtin_amdgcn_mfma_f32_16x16x32_bf16(a, bf[ks], acc[ot], 0, 0, 0);
    }
  // C frag: col(lr)=e within wave, row(ot*16+lq*4+r)=o.  swish + bf16 + short4.
  #pragma unroll
  for (int ot=0; ot<7; ++ot){
    __hip_bfloat16 hv[4];
    #pragma unroll
    for (int r=0; r<4; ++r)
      hv[r] = __float2bfloat16(swishf(acc[ot][r]));   // Wt rows o>=100 zero -> swish(0)=0
    *(short4*)&sOut[(wv*16+lr)*136 + ot*16 + lq*4] = *(short4*)hv;
  }
  // zero k = 112..127 of own rows COMPLETELY: 64 lanes = 16 rows x 4 quarters
  {
    int lane = lq*16 + lr;            // 0..63
    int row = lane & 15, q = lane >> 4;   // q in 0..3
    short4 z = {0,0,0,0};
    *(short4*)&sOut[(wv*16+row)*136 + 112 + q*4] = z;
  }
}

// stage one 16KB pre-swizzled chunk: 4 x global_load_lds(16B) per thread
__device__ __forceinline__ void stage_chunk(const __hip_bfloat16* __restrict__ W3t,
                                            int chunk, char* sW, int t)
{
  const int lane = t & 63, wv = t >> 6;
  const char* g = (const char*)W3t + (size_t)chunk*16384;
  #pragma unroll
  for (int r=0; r<4; ++r){
    const char* gsrc = g + (wv*256 + r*64 + lane)*16;
    __builtin_amdgcn_global_load_lds(
        (const __attribute__((address_space(1))) unsigned int*)gsrc,
        (__attribute__((address_space(3))) unsigned int*)(sW + wv*4096 + r*1024),
        16, 0, 0);
  }
}

template<int LO,int LI,int LF>
__device__ __forceinline__ void kv_sec(float* kvb, const float* sC3,
                                       const float* __restrict__ rshrow,
                                       int e, int role)
{
  constexpr int NO = 2*LO+1, NI = 2*LI+1, NF = 2*LF+1;
  constexpr int C3B = C3OFFT[LO][LI][LF];
  float y[NF];
  #pragma unroll
  for (int mf=0; mf<NF; ++mf) y[mf] = rshrow[LF*LF + mf];
  for (int it = role; it < NO*NI; it += 4){
    float s = 0.f;
    #pragma unroll
    for (int mf=0; mf<NF; ++mf) s += sC3[C3B + it*NF + mf] * y[mf];
    kvb[e*25 + it] = s;
  }
}

template<int LO,int LI>
__device__ __forceinline__ void consume_sec(
    const float* sRt, const float* sFf, const float* kvb, float* sAcc,
    int e, int role)
{
  constexpr int NO = 2*LO+1, NI = 2*LI+1;
  constexpr int FO = FOFFT[LI];
  float H[2][NI];
  #pragma unroll
  for (int du=0; du<2; ++du)
    #pragma unroll
    for (int mi=0; mi<NI; ++mi) H[du][mi] = 0.f;

  #pragma unroll
  for (int vg=0; vg<2; ++vg){
    float fb[4*NI];
    #pragma unroll
    for (int p=0; p<NI; ++p)
      *(f32x4*)&fb[p*4] = *(const f32x4*)&sFf[e*76 + FO + vg*4*NI + p*4];
    #pragma unroll
    for (int du=0; du<2; ++du){
      const int u = role*2 + du;
      f32x4 rv = *(const f32x4*)&sRt[e*68 + u*8 + vg*4];
      #pragma unroll
      for (int v=0; v<4; ++v)
        #pragma unroll
        for (int mi=0; mi<NI; ++mi)
          H[du][mi] += rv[v] * fb[v*NI + mi];
    }
  }
  // accumulate into group-local LDS slice (pitch 40):
  // LO=0: col=u (0..7); LO=1: col=u*3+o (0..23); LO=2: col=u*5+o (0..39)
  const int u0 = role*2, u1 = role*2 + 1;
  const int b0 = e*40 + ((LO==0) ? u0 : (LO==1) ? u0*3 : u0*5);
  const int b1 = e*40 + ((LO==0) ? u1 : (LO==1) ? u1*3 : u1*5);
  #pragma unroll
  for (int o=0; o<NO; ++o){
    float s0 = 0.f, s1 = 0.f;
    #pragma unroll
    for (int mi=0; mi<NI; ++mi){
      float kvv = kvb[e*25 + o*NI + mi];
      s0 += kvv * H[0][mi];
      s1 += kvv * H[1][mi];
    }
    sAcc[b0 + o] += s0;
    sAcc[b1 + o] += s1;
  }
}

// wave-local MFMA (r20, verified): wave computes all c' for its own 16 edges
__device__ __forceinline__ void mfma_sec(const char* sW, float* sRt,
                                         const bf16x8 (&hf)[4],
                                         int wv, int lr, int lq)
{
  f32x4 a4[4] = {};
  #pragma unroll
  for (int ks=0; ks<4; ++ks){
    #pragma unroll
    for (int ct=0; ct<4; ++ct){
      const int row = ct*16 + lr;
      const int u   = (row*16 + (ks*4 + lq)) ^ (row & 7);
      bf16x8 a = *(const bf16x8*)(sW + u*16);
      a4[ct] = __builtin_amdgcn_mfma_f32_16x16x32_bf16(a, hf[ks], a4[ct], 0, 0, 0);
    }
  }
  #pragma unroll
  for (int ct=0; ct<4; ++ct)
    *(f32x4*)&sRt[(wv*16 + lr)*68 + ct*16 + lq*4] = a4[ct];
}

// Wave-local flush of the LO-group accumulator slice.
template<int J0,int W>
__device__ __forceinline__ void flush_group(float* sAcc, float* __restrict__ msg,
                                            int eb, int t, float nrm)
{
  const int lane = t & 63, wv = t >> 6;
  __builtin_amdgcn_wave_barrier();
  for (int p = lane; p < 16*W; p += 64){
    int el = wv*16 + p/W, j = p%W;
    msg[(size_t)(eb + el)*FEATD + J0 + j] = nrm * sAcc[el*40 + j];
    sAcc[el*40 + j] = 0.f;                 // ready for next group
  }
  __builtin_amdgcn_wave_barrier();
}

// One pipelined phase: stage chunk p, kv(p), consume(p-1), drain, MFMA(p).
template<int LO,int LI,int LF,int PLO,int PLI,int PFLUSH,int CUR>
__device__ __forceinline__ void phase_pl(
    int chunk, const __hip_bfloat16* __restrict__ W3t, const bf16x8 (&hf)[4],
    char* sW, float* sRt, float* sFf, float* sKV, const float* sC3,
    const float* __restrict__ rshrow, float* sAcc,
    float* __restrict__ msg, int eb, int t)
{
  const int e = t >> 2, role = t & 3;
  const int lane = t & 63, wv = t >> 6;
  const int lr = lane & 15, lq = lane >> 4;

  __syncthreads();                       // all waves done reading sW (prev MFMA)
  stage_chunk(W3t, chunk, sW, t);        // issue coalesced stage (vmcnt)

  kv_sec<LO,LI,LF>(sKV + CUR*1600, sC3, rshrow, e, role);
  if constexpr (PLO >= 0)
    consume_sec<PLO,PLI>(sRt, sFf, sKV + (1-CUR)*1600, sAcc, e, role);
  if constexpr (PFLUSH == 0)
    flush_group<0,8>(sAcc, msg, eb, t, 0.72360125f);
  if constexpr (PFLUSH == 1)
    flush_group<8,24>(sAcc, msg, eb, t, 0.8204867f);

  __syncthreads();                       // drains vmcnt(0): sW chunk ready
  mfma_sec(sW, sRt, hf, wv, lr, lq);     // writes sRt (prev consumed above)
  __builtin_amdgcn_wave_barrier();
}

__global__ __launch_bounds__(256,2) void fused_kernel(
    const float* __restrict__ feats, const int* __restrict__ ei,
    const float* __restrict__ radii, const float* __restrict__ rsh,
    const float* __restrict__ W0,
    const __hip_bfloat16* __restrict__ W1t, const __hip_bfloat16* __restrict__ W2t,
    const __hip_bfloat16* __restrict__ W3t, const float* __restrict__ C3g,
    float* __restrict__ msg, int E)
{
  __shared__ __align__(16) char smem[SMEM_SZ];
  // fused-view pointers
  char*  sW   = smem + OF_W;
  float* sRt  = (float*)(smem + OF_RT);
  float* sAcc = (float*)(smem + OF_ACC);
  float* sFf  = (float*)(smem + OF_F);
  float* sKV  = (float*)(smem + OF_KV);
  float* sC3  = (float*)(smem + OF_C3);
  int*   sSrc = (int*)(smem + OF_SRC);
  // radial-overlay pointers (prologue only)
  char*  sWr  = smem + OF_RW;
  float* sbas = (float*)(smem + OF_BAS);
  __hip_bfloat16* hA = (__hip_bfloat16*)(smem + OF_HA);
  __hip_bfloat16* hB = (__hip_bfloat16*)(smem + OF_HB);

  const int t = threadIdx.x;
  const int eb = blockIdx.x*64;
  const int lane = t & 63, wv = t >> 6;
  const int lr = lane & 15, lq = lane >> 4;

  // ===================== radial prologue (r20 radial, in-block) ============
  stage_w(W1t, sWr, t);                  // W1 stage hides under basis + h1

  for (int p=t; p<640; p+=256){
    int er = p/10, k = p%10;
    int eg = eb + er;
    float r = (eg < E) ? radii[eg] : 0.f;
    float c = 0.7f + (2.5f/9.0f)*(float)k;
    float d = (r - c) * (9.0f/2.5f);
    sbas[p] = __expf(-d*d);
  }
  __syncthreads();
  // layer 1 (K=10, VALU), h1 bf16 into hA; zero k-pad 100..135
  for (int p=t; p<6400; p+=256){
    int er = p/100, o = p%100;
    float s = 0.f;
    #pragma unroll
    for (int k=0;k<10;++k) s += sbas[er*10+k]*W0[k*100+o];
    hA[er*136+o] = __float2bfloat16(swishf(s*0.3162277660168379f));   // 1/sqrt(10)
  }
  for (int p=t; p<64*36; p+=256){
    int er = p/36, k = 100 + p%36;
    hA[er*136+k] = __float2bfloat16(0.f);
  }
  __syncthreads();   // drains vmcnt: sWr = W1 ready; hA ready

  radial_layer_lds(hA, sWr, hB, wv, lr, lq);   // h2 = swish(0.1*h1@W1)
  __syncthreads();                             // all waves done reading W1
  stage_w(W2t, sWr, t);
  __syncthreads();                             // drains vmcnt: sWr = W2 ready
  radial_layer_lds(hB, sWr, hA, wv, lr, lq);   // h3 = swish(0.1*h2@W2)
  __builtin_amdgcn_wave_barrier();             // own rows -> hf load wave-local

  // B-fragments straight from LDS (no h_bf global roundtrip)
  bf16x8 hf[4];
  #pragma unroll
  for (int ks=0; ks<4; ++ks)
    hf[ks] = *(const bf16x8*)&hA[(wv*16+lr)*136 + ks*32 + lq*8];

  __syncthreads();   // radial overlay dead; fused buffers may now be written

  // ===================== fused init (r20) ==================================
  for (int p=t; p<2560; p+=256) sAcc[p] = 0.f;
  for (int p=t; p<64; p+=256){
    int e = eb + p;
    sSrc[p] = (e < E) ? ei[e] : 0;
  }
  for (int p=t; p<C3TOT; p+=256) sC3[p] = C3g[p];
  __syncthreads();
  for (int p=t; p<64*72; p+=256){
    int el = p/72, j = p%72;
    sFf[el*76 + j] = feats[(size_t)sSrc[el]*72 + j];
  }
  __syncthreads();

  // own-edge rsh row, pad-clamped (pad rows' msg is never read by gather)
  int eg = eb + (t >> 2); if (eg > E-1) eg = E-1;
  const float* rshrow = rsh + (size_t)eg*25;

  // pipelined phases: consume/flush lag one phase behind stage/kv/MFMA
  phase_pl<0,0,0, -1,-1, -1, 0>( 0, W3t, hf, sW, sRt, sFf, sKV, sC3, rshrow, sAcc, msg, eb, t);
  phase_pl<0,1,1,  0, 0, -1, 1>( 1, W3t, hf, sW, sRt, sFf, sKV, sC3, rshrow, sAcc, msg, eb, t);
  phase_pl<0,2,2,  0, 1, -1, 0>( 2, W3t, hf, sW, sRt, sFf, sKV, sC3, rshrow, sAcc, msg, eb, t);
  phase_pl<1,0,1,  0, 2,  0, 1>( 3, W3t, hf, sW, sRt, sFf, sKV, sC3, rshrow, sAcc, msg, eb, t);
  phase_pl<1,1,0,  1, 0, -1, 0>( 4, W3t, hf, sW, sRt, sFf, sKV, sC3, rshrow, sAcc, msg, eb, t);
  phase_pl<1,1,1,  1, 1, -1, 1>( 5, W3t, hf, sW, sRt, sFf, sKV, sC3, rshrow, sAcc, msg, eb, t);
  phase_pl<1,1,2,  1, 1, -1, 0>( 6, W3t, hf, sW, sRt, sFf, sKV, sC3, rshrow, sAcc, msg, eb, t);
  phase_pl<1,2,1,  1, 1, -1, 1>( 7, W3t, hf, sW, sRt, sFf, sKV, sC3, rshrow, sAcc, msg, eb, t);
  phase_pl<1,2,2,  1, 2, -1, 0>( 8, W3t, hf, sW, sRt, sFf, sKV, sC3, rshrow, sAcc, msg, eb, t);
  phase_pl<1,2,3,  1, 2, -1, 1>( 9, W3t, hf, sW, sRt, sFf, sKV, sC3, rshrow, sAcc, msg, eb, t);
  phase_pl<2,0,2,  1, 2,  1, 0>(10, W3t, hf, sW, sRt, sFf, sKV, sC3, rshrow, sAcc, msg, eb, t);
  phase_pl<2,1,1,  2, 0, -1, 1>(11, W3t, hf, sW, sRt, sFf, sKV, sC3, rshrow, sAcc, msg, eb, t);
  phase_pl<2,1,2,  2, 1, -1, 0>(12, W3t, hf, sW, sRt, sFf, sKV, sC3, rshrow, sAcc, msg, eb, t);
  phase_pl<2,1,3,  2, 1, -1, 1>(13, W3t, hf, sW, sRt, sFf, sKV, sC3, rshrow, sAcc, msg, eb, t);
  phase_pl<2,2,0,  2, 1, -1, 0>(14, W3t, hf, sW, sRt, sFf, sKV, sC3, rshrow, sAcc, msg, eb, t);
  phase_pl<2,2,1,  2, 2, -1, 1>(15, W3t, hf, sW, sRt, sFf, sKV, sC3, rshrow, sAcc, msg, eb, t);
  phase_pl<2,2,2,  2, 2, -1, 0>(16, W3t, hf, sW, sRt, sFf, sKV, sC3, rshrow, sAcc, msg, eb, t);
  phase_pl<2,2,3,  2, 2, -1, 1>(17, W3t, hf, sW, sRt, sFf, sKV, sC3, rshrow, sAcc, msg, eb, t);
  phase_pl<2,2,4,  2, 2, -1, 0>(18, W3t, hf, sW, sRt, sFf, sKV, sC3, rshrow, sAcc, msg, eb, t);

  // epilogue: consume phase 18 (parity 0) + final flush (sRt wave-local)
  {
    const int e = t >> 2, role = t & 3;
    consume_sec<2,2>(sRt, sFf, sKV + 0*1600, sAcc, e, role);
    flush_group<32,40>(sAcc, msg, eb, t, 0.9341652f);
  }
}

// ---------------------------------------------------------------------------
extern "C" void kernel_launch(void* const* d_in, const int* in_sizes, int n_in,
                              void* d_out, int out_size, void* d_ws, size_t ws_size,
                              hipStream_t stream)
{
  const float* feats = (const float*)d_in[0];
  const int*   ei    = (const int*)d_in[1];
  const float* radii = (const float*)d_in[2];
  const float* rsh   = (const float*)d_in[3];
  const float* W0    = (const float*)d_in[4];
  const float* W1    = (const float*)d_in[5];
  const float* W2    = (const float*)d_in[6];
  const float* W3    = (const float*)d_in[7];
  float* out = (float*)d_out;
  const int E = in_sizes[2];
  const int N = in_sizes[0]/FEATD;

  const int EPAD = ((E + 63)/64)*64;
  const int NBLK = EPAD/64;

  char* ws = (char*)d_ws;
  size_t off_b = 0;
  float*  C3f = (float*)(ws + off_b);  off_b += 8192;
  __hip_bfloat16* W3t = (__hip_bfloat16*)(ws + off_b); off_b += 335872;  // 19*16KB used
  __hip_bfloat16* W1t = (__hip_bfloat16*)(ws + off_b); off_b += 30720;   // 112*128 bf16 (28672 used)
  __hip_bfloat16* W2t = (__hip_bfloat16*)(ws + off_b); off_b += 30720;
  float* msg = (float*)(ws + off_b);   off_b += (size_t)EPAD*FEATD*4;
  int* deg    = (int*)(ws + off_b);    off_b += (size_t)N*4;
  int* offv   = (int*)(ws + off_b);    off_b += (size_t)(N+1)*4;
  int* cursor = (int*)(ws + off_b);    off_b += (size_t)N*4;
  int* eid    = (int*)(ws + off_b);    off_b += (size_t)E*4;

  // constants / tables (merged)
  c3_combined_kernel<<<dim3(NCOMBO), dim3(64), 0, stream>>>(C3f);
  prep_combined_kernel<<<dim3((1216*128 + 2*112*128 + 255)/256), dim3(256), 0, stream>>>(
      W3, W1, W2, W3t, W1t, W2t);

  // CSR of edges by target
  hipMemsetAsync(deg, 0, (size_t)N*4, stream);
  hist_kernel<<<dim3((E+255)/256), dim3(256), 0, stream>>>(ei, deg, E);
  scan_kernel<<<dim3(1), dim3(256), 0, stream>>>(deg, offv, cursor, N, E);
  fill_kernel<<<dim3((E+255)/256), dim3(256), 0, stream>>>(ei, cursor, eid, E);

  // main pipeline (radial fused in)
  fused_kernel<<<dim3(NBLK), dim3(256), 0, stream>>>(
      feats, ei, radii, rsh, W0, W1t, W2t, W3t, C3f, msg, E);
  gather_kernel<<<dim3(N), dim3(64), 0, stream>>>(msg, offv, eid, out, N);
}

// Round 9
// 340.826 us; speedup vs baseline: 1.1891x; 1.1891x over previous
//
#include <hip/hip_runtime.h>
#include <hip/hip_bf16.h>
#include <math.h>

// ============================================================================
// MinimalNetwork, round 23: delete the msg/CSR/gather subsystem.
// r22 post-mortem: fused absorbed radial ~1:1 (total 374->405, fused 155->200)
// and the ~200us OUTSIDE fused is the unprofiled tail: gather (57MB msg
// roundtrip), CSR trio (single-block scan = GPU-wide serialization), c3, prep,
// dispatch gaps. Change:
//   - flush_group does atomicAdd(out[tgt*72+j], nrm*acc) directly (7.2M fp32
//     atomics, avg degree 5, adjacent lanes -> same cache line). Pad edges
//     guarded (eg<E). out zeroed by hipMemsetAsync inside the graph.
//   - REMOVED: msg buffer, gather, hist, scan, fill, deg/offv/cursor/eid.
//   - dispatches 8 -> 4 (memset, c3_combined, prep_combined, fused).
// Fused compute internals byte-identical to r22 (passing).
// Kill criteria: total>=380 or fused>=240 -> revert to msg+gather; absmax
// fail -> r22 revert.
// ============================================================================

#define FEATD 72
#define NCOL 1216
#define SWISH_SCALE 1.679177f

typedef __attribute__((ext_vector_type(8))) short bf16x8;
typedef __attribute__((ext_vector_type(4))) float f32x4;

// ---- 19 (lo,li,lf) chunks; CB_OFF = offsets into the C3 coefficient pool ----
constexpr int NCOMBO = 19;
constexpr int CB_LO[NCOMBO] = {0,0,0,1,1,1,1,1,1,1,2,2,2,2,2,2,2,2,2};
constexpr int CB_LI[NCOMBO] = {0,1,2,0,1,1,1,2,2,2,0,1,1,1,2,2,2,2,2};
constexpr int CB_LF[NCOMBO] = {0,1,2,1,0,1,2,1,2,3,2,1,2,3,0,1,2,3,4};
constexpr int CB_OFF[NCOMBO] = {0,1,10,35,44,53,80,125,170,245,350,375,420,495,600,625,700,825,1000};
constexpr int CB_SZ[NCOMBO]  = {1,9,25,9,9,27,45,45,75,105,25,45,75,105,25,75,125,175,225};
constexpr int C3TOT = 1225;

constexpr int C3OFFT[3][3][5] = {
  { {0,-1,-1,-1,-1}, {-1,1,-1,-1,-1}, {-1,-1,10,-1,-1} },
  { {-1,35,-1,-1,-1}, {44,53,80,-1,-1}, {-1,125,170,245,-1} },
  { {-1,-1,350,-1,-1}, {-1,375,420,495,-1}, {600,625,700,825,1000} }
};
constexpr int ROFFT[3][3] = {{0,64,128},{192,256,448},{640,704,896}};
constexpr int FOFFT[3]   = {0,8,32};

__device__ const double d_fact[11] = {1.,1.,2.,6.,24.,120.,720.,5040.,40320.,362880.,3628800.};

// ---------------------------------------------------------------------------
// Wigner 3j (complex basis, Racah) in double precision + real change of basis
// ---------------------------------------------------------------------------
__device__ double w3j_entry(int j1,int j2,int j3,int m1,int m2,int m3){
  if (m1+m2+m3 != 0) return 0.0;
  int dj = j1-j2; if (dj<0) dj=-dj;
  if (j3 < dj || j3 > j1+j2) return 0.0;
  int t1 = j2 - m1 - j3, t2 = j1 + m2 - j3;
  int kmin = 0; if (t1>kmin) kmin=t1; if (t2>kmin) kmin=t2;
  int kmax = j1+j2-j3; if (j1-m1<kmax) kmax=j1-m1; if (j2+m2<kmax) kmax=j2+m2;
  double s = 0.0;
  for (int k=kmin;k<=kmax;++k){
    double den = d_fact[k]*d_fact[k-t1]*d_fact[k-t2]*d_fact[j1+j2-j3-k]
               * d_fact[j1-m1-k]*d_fact[j2+m2-k];
    s += ((k&1)? -1.0:1.0)/den;
  }
  double pref = sqrt(d_fact[j1+j2-j3]*d_fact[j1-j2+j3]*d_fact[-j1+j2+j3]/d_fact[j1+j2+j3+1]
               * d_fact[j1+m1]*d_fact[j1-m1]*d_fact[j2+m2]*d_fact[j2-m2]
               * d_fact[j3+m3]*d_fact[j3-m3]);
  int ex = j1-j2-m3;
  if (ex & 1) pref = -pref;
  return pref*s;
}

__device__ void cob(int l, int r, int c, double& re, double& im){
  re = 0.0; im = 0.0;
  int mr = r - l, mc = c - l;
  const double s = 0.70710678118654752440;
  if (mr == 0) { if (mc == 0) re = 1.0; return; }
  if (mr > 0) {
    if (mc == mr)       re = (mr & 1) ? -s : s;
    else if (mc == -mr) re = s;
  } else {
    int m = -mr;
    if (mc == -m)      im = s;
    else if (mc == m)  im = (m & 1) ? s : -s;
  }
}

// One block per chunk: compute all elements in LDS (double), normalize, emit.
__global__ void c3_combined_kernel(float* __restrict__ C3f){
  __shared__ double sre[225], sim[225];
  const int c = blockIdx.x;
  const int lo = CB_LO[c], li = CB_LI[c], lf = CB_LF[c];
  const int off = CB_OFF[c], sz = CB_SZ[c];
  const int n2 = 2*li+1, n3 = 2*lf+1;
  const int t = threadIdx.x;

  for (int p=t; p<sz; p+=64){
    int a = p/(n2*n3), b = (p/n3)%n2, g = p%n3;
    double re=0.0, im=0.0;
    for (int m1=-lo; m1<=lo; ++m1){
      for (int m2=-li; m2<=li; ++m2){
        int m3 = -m1-m2;
        if (m3 < -lf || m3 > lf) continue;
        double w = w3j_entry(lo,li,lf,m1,m2,m3);
        if (w == 0.0) continue;
        double r1,i1,r2,i2,r3,i3;
        cob(lo, a, m1+lo, r1,i1);
        cob(li, b, m2+li, r2,i2);
        cob(lf, g, m3+lf, r3,i3);
        double rr = r1*r2 - i1*i2, ri = r1*i2 + i1*r2;
        double fr = rr*r3 - ri*i3, fi = rr*i3 + ri*r3;
        re += fr*w; im += fi*w;
      }
    }
    sre[p] = re; sim[p] = im;
  }
  __syncthreads();
  double s2r=0.0, s2i=0.0;
  for (int p=t; p<sz; p+=64){ double x=sre[p], y=sim[p]; s2r+=x*x; s2i+=y*y; }
  for (int m=1; m<64; m<<=1){ s2r += __shfl_xor(s2r, m, 64); s2i += __shfl_xor(s2i, m, 64); }
  bool useRe = (s2r >= s2i);
  double n = sqrt(useRe ? s2r : s2i);
  double inv = (n > 0.0) ? 1.0/n : 1.0;
  for (int p=t; p<sz; p+=64){
    double v = useRe ? sre[p] : sim[p];
    C3f[off+p] = (float)(v*inv);
  }
}

// ---------------------------------------------------------------------------
// Combined weight repack (idx-routed): W3t chunks + W1t/W2t, all pitch-128,
// 0.1 folded, PRE-SWIZZLED: unit16 = (row*16 + (k>>3)) ^ (row&7).
// ---------------------------------------------------------------------------
__global__ __launch_bounds__(256) void prep_combined_kernel(
    const float* __restrict__ W3, const float* __restrict__ W1,
    const float* __restrict__ W2, __hip_bfloat16* __restrict__ W3t,
    __hip_bfloat16* __restrict__ W1t, __hip_bfloat16* __restrict__ W2t)
{
  int idx = blockIdx.x*256 + threadIdx.x;
  constexpr int NW3 = 1216*128;      // 155648
  constexpr int HALF = 112*128;      // 14336
  if (idx < NW3){
    int cp = idx >> 7, k = idx & 127;
    int chunk = cp >> 6, r = cp & 63;
    int lo = CB_LO[chunk], li = CB_LI[chunk], lf = CB_LF[chunk];
    int lmin = lo<li ? lo : li;
    int nlf = 2*lmin+1;
    int fi = lf - (lo>li ? lo-li : li-lo);
    int c = ROFFT[lo][li] + r*nlf + fi;
    float v = (k < 100) ? 0.1f*W3[(size_t)k*NCOL + c] : 0.f;
    int swz = (r*16 + (k>>3)) ^ (r&7);
    W3t[(size_t)chunk*8192 + swz*8 + (k&7)] = __float2bfloat16(v);
  } else if (idx < NW3 + 2*HALF){
    int r2 = idx - NW3;
    const float* W = (r2 < HALF) ? W1 : W2;
    __hip_bfloat16* Wt = (r2 < HALF) ? W1t : W2t;
    int r = (r2 < HALF) ? r2 : r2 - HALF;
    int o = r >> 7, k = r & 127;
    float v = (o < 100 && k < 100) ? 0.1f*W[k*100+o] : 0.f;
    int swz = (o*16 + (k>>3)) ^ (o&7);
    Wt[swz*8 + (k&7)] = __float2bfloat16(v);
  }
}

// ---------------------------------------------------------------------------
// Fused radial + GEMM + TP + atomic scatter-add. LDS 81700 B, 2 blocks/CU.
// ---------------------------------------------------------------------------
constexpr int OF_W   = 0;         // 16384: staged W3t chunk (swizzled)
constexpr int OF_RT  = 16384;     // 64*68 f32 = 17408
constexpr int OF_ACC = 33792;     // 64*40 f32 = 10240 (live LO-group slice)
constexpr int OF_F   = 44032;     // 64*76 f32 = 19456
constexpr int OF_KV  = 63488;     // 2 x 64*25 f32 = 12800 (double-buffered)
constexpr int OF_C3  = 76288;     // 1225 f32 = 4900
constexpr int OF_SRC = 81188;     // 64 int = 256
constexpr int OF_TGT = 81444;     // 64 int = 256
constexpr int SMEM_SZ = 81700;    // <= 81920 -> 2 blocks/CU

// radial overlay (prologue only; fused buffers below 66048 dead then)
constexpr int OF_RW   = 0;        // 28672: staged W1t/W2t
constexpr int OF_BAS  = 28672;    // 640 f32 = 2560
constexpr int OF_HA   = 31232;    // 64*136 bf16 = 17408
constexpr int OF_HB   = 48640;    // 64*136 bf16 = 17408 -> ends 66048

__device__ __forceinline__ float swishf(float s){
  return SWISH_SCALE * s / (1.f + __expf(-s));
}

// stage 28672B pre-swizzled Wt: 7 x global_load_lds(16B) per thread
__device__ __forceinline__ void stage_w(const __hip_bfloat16* __restrict__ Wt,
                                        char* sW, int t)
{
  const int lane = t & 63, wv = t >> 6;
  const char* g = (const char*)Wt;
  #pragma unroll
  for (int i=0; i<7; ++i){
    const char* gsrc = g + (i*256 + wv*64 + lane)*16;
    __builtin_amdgcn_global_load_lds(
        (const __attribute__((address_space(1))) unsigned int*)gsrc,
        (__attribute__((address_space(3))) unsigned int*)(sW + i*4096 + wv*1024),
        16, 0, 0);
  }
}

__device__ __forceinline__ void radial_layer_lds(
    const __hip_bfloat16* __restrict__ sIn,   // [64][136] bf16, rows e
    const char* __restrict__ sW,              // staged Wt (swizzled, pitch 128)
    __hip_bfloat16* __restrict__ sOut,        // [64][136] bf16
    int wv, int lr, int lq)
{
  bf16x8 bf[4];
  #pragma unroll
  for (int ks=0; ks<4; ++ks)
    bf[ks] = *(const bf16x8*)&sIn[(wv*16+lr)*136 + ks*32 + lq*8];
  f32x4 acc[7] = {};
  #pragma unroll
  for (int ks=0; ks<4; ++ks)
    #pragma unroll
    for (int ot=0; ot<7; ++ot){
      const int row = ot*16 + lr;
      const int u = (row*16 + ks*4 + lq) ^ (row & 7);
      bf16x8 a = *(const bf16x8*)(sW + u*16);
      acc[ot] = __builtin_amdgcn_mfma_f32_16x16x32_bf16(a, bf[ks], acc[ot], 0, 0, 0);
    }
  // C frag: col(lr)=e within wave, row(ot*16+lq*4+r)=o.  swish + bf16 + short4.
  #pragma unroll
  for (int ot=0; ot<7; ++ot){
    __hip_bfloat16 hv[4];
    #pragma unroll
    for (int r=0; r<4; ++r)
      hv[r] = __float2bfloat16(swishf(acc[ot][r]));   // Wt rows o>=100 zero -> swish(0)=0
    *(short4*)&sOut[(wv*16+lr)*136 + ot*16 + lq*4] = *(short4*)hv;
  }
  // zero k = 112..127 of own rows COMPLETELY: 64 lanes = 16 rows x 4 quarters
  {
    int lane = lq*16 + lr;            // 0..63
    int row = lane & 15, q = lane >> 4;   // q in 0..3
    short4 z = {0,0,0,0};
    *(short4*)&sOut[(wv*16+row)*136 + 112 + q*4] = z;
  }
}

// stage one 16KB pre-swizzled chunk: 4 x global_load_lds(16B) per thread
__device__ __forceinline__ void stage_chunk(const __hip_bfloat16* __restrict__ W3t,
                                            int chunk, char* sW, int t)
{
  const int lane = t & 63, wv = t >> 6;
  const char* g = (const char*)W3t + (size_t)chunk*16384;
  #pragma unroll
  for (int r=0; r<4; ++r){
    const char* gsrc = g + (wv*256 + r*64 + lane)*16;
    __builtin_amdgcn_global_load_lds(
        (const __attribute__((address_space(1))) unsigned int*)gsrc,
        (__attribute__((address_space(3))) unsigned int*)(sW + wv*4096 + r*1024),
        16, 0, 0);
  }
}

template<int LO,int LI,int LF>
__device__ __forceinline__ void kv_sec(float* kvb, const float* sC3,
                                       const float* __restrict__ rshrow,
                                       int e, int role)
{
  constexpr int NO = 2*LO+1, NI = 2*LI+1, NF = 2*LF+1;
  constexpr int C3B = C3OFFT[LO][LI][LF];
  float y[NF];
  #pragma unroll
  for (int mf=0; mf<NF; ++mf) y[mf] = rshrow[LF*LF + mf];
  for (int it = role; it < NO*NI; it += 4){
    float s = 0.f;
    #pragma unroll
    for (int mf=0; mf<NF; ++mf) s += sC3[C3B + it*NF + mf] * y[mf];
    kvb[e*25 + it] = s;
  }
}

template<int LO,int LI>
__device__ __forceinline__ void consume_sec(
    const float* sRt, const float* sFf, const float* kvb, float* sAcc,
    int e, int role)
{
  constexpr int NO = 2*LO+1, NI = 2*LI+1;
  constexpr int FO = FOFFT[LI];
  float H[2][NI];
  #pragma unroll
  for (int du=0; du<2; ++du)
    #pragma unroll
    for (int mi=0; mi<NI; ++mi) H[du][mi] = 0.f;

  #pragma unroll
  for (int vg=0; vg<2; ++vg){
    float fb[4*NI];
    #pragma unroll
    for (int p=0; p<NI; ++p)
      *(f32x4*)&fb[p*4] = *(const f32x4*)&sFf[e*76 + FO + vg*4*NI + p*4];
    #pragma unroll
    for (int du=0; du<2; ++du){
      const int u = role*2 + du;
      f32x4 rv = *(const f32x4*)&sRt[e*68 + u*8 + vg*4];
      #pragma unroll
      for (int v=0; v<4; ++v)
        #pragma unroll
        for (int mi=0; mi<NI; ++mi)
          H[du][mi] += rv[v] * fb[v*NI + mi];
    }
  }
  // accumulate into group-local LDS slice (pitch 40):
  // LO=0: col=u (0..7); LO=1: col=u*3+o (0..23); LO=2: col=u*5+o (0..39)
  const int u0 = role*2, u1 = role*2 + 1;
  const int b0 = e*40 + ((LO==0) ? u0 : (LO==1) ? u0*3 : u0*5);
  const int b1 = e*40 + ((LO==0) ? u1 : (LO==1) ? u1*3 : u1*5);
  #pragma unroll
  for (int o=0; o<NO; ++o){
    float s0 = 0.f, s1 = 0.f;
    #pragma unroll
    for (int mi=0; mi<NI; ++mi){
      float kvv = kvb[e*25 + o*NI + mi];
      s0 += kvv * H[0][mi];
      s1 += kvv * H[1][mi];
    }
    sAcc[b0 + o] += s0;
    sAcc[b1 + o] += s1;
  }
}

// wave-local MFMA (r20, verified): wave computes all c' for its own 16 edges
__device__ __forceinline__ void mfma_sec(const char* sW, float* sRt,
                                         const bf16x8 (&hf)[4],
                                         int wv, int lr, int lq)
{
  f32x4 a4[4] = {};
  #pragma unroll
  for (int ks=0; ks<4; ++ks){
    #pragma unroll
    for (int ct=0; ct<4; ++ct){
      const int row = ct*16 + lr;
      const int u   = (row*16 + (ks*4 + lq)) ^ (row & 7);
      bf16x8 a = *(const bf16x8*)(sW + u*16);
      a4[ct] = __builtin_amdgcn_mfma_f32_16x16x32_bf16(a, hf[ks], a4[ct], 0, 0, 0);
    }
  }
  #pragma unroll
  for (int ct=0; ct<4; ++ct)
    *(f32x4*)&sRt[(wv*16 + lr)*68 + ct*16 + lq*4] = a4[ct];
}

// Wave-local flush: atomic scatter-add of the LO-group slice into out.
// sAcc rows 16wv..16wv+15 are written only by wave wv (no block sync needed).
template<int J0,int W>
__device__ __forceinline__ void flush_group(float* sAcc, float* __restrict__ out,
                                            const int* sTgt, int eb, int t,
                                            float nrm, int E)
{
  const int lane = t & 63, wv = t >> 6;
  __builtin_amdgcn_wave_barrier();
  for (int p = lane; p < 16*W; p += 64){
    int el = wv*16 + p/W, j = p%W;
    if (eb + el < E)
      atomicAdd(&out[(size_t)sTgt[el]*FEATD + J0 + j], nrm * sAcc[el*40 + j]);
    sAcc[el*40 + j] = 0.f;                 // ready for next group
  }
  __builtin_amdgcn_wave_barrier();
}

// One pipelined phase: stage chunk p, kv(p), consume(p-1), drain, MFMA(p).
template<int LO,int LI,int LF,int PLO,int PLI,int PFLUSH,int CUR>
__device__ __forceinline__ void phase_pl(
    int chunk, const __hip_bfloat16* __restrict__ W3t, const bf16x8 (&hf)[4],
    char* sW, float* sRt, float* sFf, float* sKV, const float* sC3,
    const float* __restrict__ rshrow, float* sAcc,
    float* __restrict__ out, const int* sTgt, int eb, int t, int E)
{
  const int e = t >> 2, role = t & 3;
  const int lane = t & 63, wv = t >> 6;
  const int lr = lane & 15, lq = lane >> 4;

  __syncthreads();                       // all waves done reading sW (prev MFMA)
  stage_chunk(W3t, chunk, sW, t);        // issue coalesced stage (vmcnt)

  kv_sec<LO,LI,LF>(sKV + CUR*1600, sC3, rshrow, e, role);
  if constexpr (PLO >= 0)
    consume_sec<PLO,PLI>(sRt, sFf, sKV + (1-CUR)*1600, sAcc, e, role);
  if constexpr (PFLUSH == 0)
    flush_group<0,8>(sAcc, out, sTgt, eb, t, 0.72360125f, E);
  if constexpr (PFLUSH == 1)
    flush_group<8,24>(sAcc, out, sTgt, eb, t, 0.8204867f, E);

  __syncthreads();                       // drains vmcnt(0): sW chunk ready
  mfma_sec(sW, sRt, hf, wv, lr, lq);     // writes sRt (prev consumed above)
  __builtin_amdgcn_wave_barrier();
}

__global__ __launch_bounds__(256,2) void fused_kernel(
    const float* __restrict__ feats, const int* __restrict__ ei,
    const float* __restrict__ radii, const float* __restrict__ rsh,
    const float* __restrict__ W0,
    const __hip_bfloat16* __restrict__ W1t, const __hip_bfloat16* __restrict__ W2t,
    const __hip_bfloat16* __restrict__ W3t, const float* __restrict__ C3g,
    float* __restrict__ out, int E)
{
  __shared__ __align__(16) char smem[SMEM_SZ];
  // fused-view pointers
  char*  sW   = smem + OF_W;
  float* sRt  = (float*)(smem + OF_RT);
  float* sAcc = (float*)(smem + OF_ACC);
  float* sFf  = (float*)(smem + OF_F);
  float* sKV  = (float*)(smem + OF_KV);
  float* sC3  = (float*)(smem + OF_C3);
  int*   sSrc = (int*)(smem + OF_SRC);
  int*   sTgt = (int*)(smem + OF_TGT);
  // radial-overlay pointers (prologue only)
  char*  sWr  = smem + OF_RW;
  float* sbas = (float*)(smem + OF_BAS);
  __hip_bfloat16* hA = (__hip_bfloat16*)(smem + OF_HA);
  __hip_bfloat16* hB = (__hip_bfloat16*)(smem + OF_HB);

  const int t = threadIdx.x;
  const int eb = blockIdx.x*64;
  const int lane = t & 63, wv = t >> 6;
  const int lr = lane & 15, lq = lane >> 4;

  // ===================== radial prologue (r22, passing) ====================
  stage_w(W1t, sWr, t);                  // W1 stage hides under basis + h1

  for (int p=t; p<640; p+=256){
    int er = p/10, k = p%10;
    int eg = eb + er;
    float r = (eg < E) ? radii[eg] : 0.f;
    float c = 0.7f + (2.5f/9.0f)*(float)k;
    float d = (r - c) * (9.0f/2.5f);
    sbas[p] = __expf(-d*d);
  }
  __syncthreads();
  // layer 1 (K=10, VALU), h1 bf16 into hA; zero k-pad 100..135
  for (int p=t; p<6400; p+=256){
    int er = p/100, o = p%100;
    float s = 0.f;
    #pragma unroll
    for (int k=0;k<10;++k) s += sbas[er*10+k]*W0[k*100+o];
    hA[er*136+o] = __float2bfloat16(swishf(s*0.3162277660168379f));   // 1/sqrt(10)
  }
  for (int p=t; p<64*36; p+=256){
    int er = p/36, k = 100 + p%36;
    hA[er*136+k] = __float2bfloat16(0.f);
  }
  __syncthreads();   // drains vmcnt: sWr = W1 ready; hA ready

  radial_layer_lds(hA, sWr, hB, wv, lr, lq);   // h2 = swish(0.1*h1@W1)
  __syncthreads();                             // all waves done reading W1
  stage_w(W2t, sWr, t);
  __syncthreads();                             // drains vmcnt: sWr = W2 ready
  radial_layer_lds(hB, sWr, hA, wv, lr, lq);   // h3 = swish(0.1*h2@W2)
  __builtin_amdgcn_wave_barrier();             // own rows -> hf load wave-local

  // B-fragments straight from LDS (no h_bf global roundtrip)
  bf16x8 hf[4];
  #pragma unroll
  for (int ks=0; ks<4; ++ks)
    hf[ks] = *(const bf16x8*)&hA[(wv*16+lr)*136 + ks*32 + lq*8];

  __syncthreads();   // radial overlay dead; fused buffers may now be written

  // ===================== fused init ========================================
  for (int p=t; p<2560; p+=256) sAcc[p] = 0.f;
  for (int p=t; p<64; p+=256){
    int e = eb + p;
    sSrc[p] = (e < E) ? ei[e] : 0;
    sTgt[p] = (e < E) ? ei[E + e] : 0;
  }
  for (int p=t; p<C3TOT; p+=256) sC3[p] = C3g[p];
  __syncthreads();
  for (int p=t; p<64*72; p+=256){
    int el = p/72, j = p%72;
    sFf[el*76 + j] = feats[(size_t)sSrc[el]*72 + j];
  }
  __syncthreads();

  // own-edge rsh row, pad-clamped (pad rows never flushed: eg<E guard)
  int eg = eb + (t >> 2); if (eg > E-1) eg = E-1;
  const float* rshrow = rsh + (size_t)eg*25;

  // pipelined phases: consume/flush lag one phase behind stage/kv/MFMA
  phase_pl<0,0,0, -1,-1, -1, 0>( 0, W3t, hf, sW, sRt, sFf, sKV, sC3, rshrow, sAcc, out, sTgt, eb, t, E);
  phase_pl<0,1,1,  0, 0, -1, 1>( 1, W3t, hf, sW, sRt, sFf, sKV, sC3, rshrow, sAcc, out, sTgt, eb, t, E);
  phase_pl<0,2,2,  0, 1, -1, 0>( 2, W3t, hf, sW, sRt, sFf, sKV, sC3, rshrow, sAcc, out, sTgt, eb, t, E);
  phase_pl<1,0,1,  0, 2,  0, 1>( 3, W3t, hf, sW, sRt, sFf, sKV, sC3, rshrow, sAcc, out, sTgt, eb, t, E);
  phase_pl<1,1,0,  1, 0, -1, 0>( 4, W3t, hf, sW, sRt, sFf, sKV, sC3, rshrow, sAcc, out, sTgt, eb, t, E);
  phase_pl<1,1,1,  1, 1, -1, 1>( 5, W3t, hf, sW, sRt, sFf, sKV, sC3, rshrow, sAcc, out, sTgt, eb, t, E);
  phase_pl<1,1,2,  1, 1, -1, 0>( 6, W3t, hf, sW, sRt, sFf, sKV, sC3, rshrow, sAcc, out, sTgt, eb, t, E);
  phase_pl<1,2,1,  1, 1, -1, 1>( 7, W3t, hf, sW, sRt, sFf, sKV, sC3, rshrow, sAcc, out, sTgt, eb, t, E);
  phase_pl<1,2,2,  1, 2, -1, 0>( 8, W3t, hf, sW, sRt, sFf, sKV, sC3, rshrow, sAcc, out, sTgt, eb, t, E);
  phase_pl<1,2,3,  1, 2, -1, 1>( 9, W3t, hf, sW, sRt, sFf, sKV, sC3, rshrow, sAcc, out, sTgt, eb, t, E);
  phase_pl<2,0,2,  1, 2,  1, 0>(10, W3t, hf, sW, sRt, sFf, sKV, sC3, rshrow, sAcc, out, sTgt, eb, t, E);
  phase_pl<2,1,1,  2, 0, -1, 1>(11, W3t, hf, sW, sRt, sFf, sKV, sC3, rshrow, sAcc, out, sTgt, eb, t, E);
  phase_pl<2,1,2,  2, 1, -1, 0>(12, W3t, hf, sW, sRt, sFf, sKV, sC3, rshrow, sAcc, out, sTgt, eb, t, E);
  phase_pl<2,1,3,  2, 1, -1, 1>(13, W3t, hf, sW, sRt, sFf, sKV, sC3, rshrow, sAcc, out, sTgt, eb, t, E);
  phase_pl<2,2,0,  2, 1, -1, 0>(14, W3t, hf, sW, sRt, sFf, sKV, sC3, rshrow, sAcc, out, sTgt, eb, t, E);
  phase_pl<2,2,1,  2, 2, -1, 1>(15, W3t, hf, sW, sRt, sFf, sKV, sC3, rshrow, sAcc, out, sTgt, eb, t, E);
  phase_pl<2,2,2,  2, 2, -1, 0>(16, W3t, hf, sW, sRt, sFf, sKV, sC3, rshrow, sAcc, out, sTgt, eb, t, E);
  phase_pl<2,2,3,  2, 2, -1, 1>(17, W3t, hf, sW, sRt, sFf, sKV, sC3, rshrow, sAcc, out, sTgt, eb, t, E);
  phase_pl<2,2,4,  2, 2, -1, 0>(18, W3t, hf, sW, sRt, sFf, sKV, sC3, rshrow, sAcc, out, sTgt, eb, t, E);

  // epilogue: consume phase 18 (parity 0) + final flush (sRt wave-local)
  {
    const int e = t >> 2, role = t & 3;
    consume_sec<2,2>(sRt, sFf, sKV + 0*1600, sAcc, e, role);
    flush_group<32,40>(sAcc, out, sTgt, eb, t, 0.9341652f, E);
  }
}

// ---------------------------------------------------------------------------
extern "C" void kernel_launch(void* const* d_in, const int* in_sizes, int n_in,
                              void* d_out, int out_size, void* d_ws, size_t ws_size,
                              hipStream_t stream)
{
  const float* feats = (const float*)d_in[0];
  const int*   ei    = (const int*)d_in[1];
  const float* radii = (const float*)d_in[2];
  const float* rsh   = (const float*)d_in[3];
  const float* W0    = (const float*)d_in[4];
  const float* W1    = (const float*)d_in[5];
  const float* W2    = (const float*)d_in[6];
  const float* W3    = (const float*)d_in[7];
  float* out = (float*)d_out;
  const int E = in_sizes[2];

  const int EPAD = ((E + 63)/64)*64;
  const int NBLK = EPAD/64;

  char* ws = (char*)d_ws;
  size_t off_b = 0;
  float*  C3f = (float*)(ws + off_b);  off_b += 8192;
  __hip_bfloat16* W3t = (__hip_bfloat16*)(ws + off_b); off_b += 335872;  // 19*16KB used
  __hip_bfloat16* W1t = (__hip_bfloat16*)(ws + off_b); off_b += 30720;   // 112*128 bf16 (28672 used)
  __hip_bfloat16* W2t = (__hip_bfloat16*)(ws + off_b); off_b += 30720;

  // out accumulates via atomics -> zero it inside the graph
  hipMemsetAsync(out, 0, (size_t)out_size*sizeof(float), stream);

  // constants / tables (merged)
  c3_combined_kernel<<<dim3(NCOMBO), dim3(64), 0, stream>>>(C3f);
  prep_combined_kernel<<<dim3((1216*128 + 2*112*128 + 255)/256), dim3(256), 0, stream>>>(
      W3, W1, W2, W3t, W1t, W2t);

  // main pipeline: fused radial + GEMM + TP + atomic scatter-add
  fused_kernel<<<dim3(NBLK), dim3(256), 0, stream>>>(
      feats, ei, radii, rsh, W0, W1t, W2t, W3t, C3f, out, E);
}